// Round 5
// baseline (500.991 us; speedup 1.0000x reference)
//
#include <hip/hip_runtime.h>
#include <hip/hip_fp16.h>

// ColorDeformConv2d — round 5: atomic-free, sync-free-K-loop design.
// prep: weight repack to MFMA frag-order bf16 (k' = tap*64+ci)
// kx:   zero-padded bf16 copy of x: xpad[b][ch][130][132] (matches reference xp)
// k2:   fused 1x1 conv -> fused2 [b][ch][16384] bf16
// k_pm: offset/mask GEMM -> u bf16 [27][b*16384+h*128+px] (bias included)
// k3:   block=(h,b), 512 thr, 2 blocks/CU. Fused rows h-1..h+1 in LDS
//       (XOR-swizzled, b-frags via ds_read_b128). Per mc: U-GEMM (no syncs),
//       epilogue tanh+bilinear(from xpad)+modulate in regs, out-GEMM with
//       B-frags built from C-regs via shfl_xor(32). Final pair-reduce, store.

typedef __attribute__((ext_vector_type(8))) __bf16 bf16x8;
typedef __attribute__((ext_vector_type(16))) float f32x16;
#define MFMA32(a, b, c) __builtin_amdgcn_mfma_f32_32x32x16_bf16((a), (b), (c), 0, 0, 0)

#define WS_AC    0
#define WS_APM   368640
#define WS_ACONV 387072
#define WS_WCD   428032
#define WS_F2    436224
#define WS_U     4630528
#define WS_XPAD  6400000
#define XPLANE   17160     // 130*132

__device__ __forceinline__ unsigned short f2bf(float f) {
    unsigned u = __float_as_uint(f);
    return (unsigned short)((u + 0x7FFFu + ((u >> 16) & 1u)) >> 16);   // RNE
}
__device__ __forceinline__ float bf2f(unsigned short s) {
    return __uint_as_float(((unsigned)s) << 16);
}
__device__ __forceinline__ unsigned pk16(float lo, float hi) {
    return (unsigned)f2bf(lo) | ((unsigned)f2bf(hi) << 16);
}
__device__ __forceinline__ bf16x8 u4bf(uint4 v) {
    union { uint4 u; bf16x8 b; } cv; cv.u = v; return cv.b;
}
__device__ __forceinline__ float fast_rcp(float x) {
#if __has_builtin(__builtin_amdgcn_rcpf)
    return __builtin_amdgcn_rcpf(x);
#else
    return 1.0f / x;
#endif
}
__device__ __forceinline__ float fast_tanh(float x) {
    float t = __expf(2.0f * x);
    return 1.0f - 2.0f * fast_rcp(t + 1.0f);
}
__device__ __forceinline__ float fast_sigmoid(float x) {
    return fast_rcp(1.0f + __expf(-x));
}

// ---------------- prep: weight repack (same as r4) ----------------
__global__ void prep_kernel(const float* __restrict__ w_c, const float* __restrict__ w_p,
                            const float* __restrict__ w_m, const float* __restrict__ w_conv,
                            const float* __restrict__ w_cd, unsigned short* __restrict__ ws) {
    int i = blockIdx.x * 256 + threadIdx.x;
    if (i >= 436224) return;
    float val;
    if (i < WS_APM) {
        int t = i, j = t & 7, l = (t >> 3) & 63, r = t >> 9, ks = r % 36, gmt = r / 36;
        int row = gmt * 32 + (l & 31);
        int kp = ks * 16 + (l >> 5) * 8 + j, tap = kp >> 6, ci = kp & 63;
        val = (row < 576) ? w_c[row * 576 + ci * 9 + tap] : 0.0f;
    } else if (i < WS_ACONV) {
        int t = i - WS_APM, j = t & 7, l = (t >> 3) & 63, ks = t >> 9;
        int row = l & 31;
        int kp = ks * 16 + (l >> 5) * 8 + j, tap = kp >> 6, ci = kp & 63;
        val = (row < 18) ? w_p[row * 576 + ci * 9 + tap]
            : (row < 27) ? w_m[(row - 18) * 576 + ci * 9 + tap] : 0.0f;
    } else if (i < WS_WCD) {
        int t = i - WS_ACONV, j = t & 7, l = (t >> 3) & 63, r = t >> 9;
        int gks = r % 40, ocT = r / 40;
        int oc = ocT * 32 + (l & 31);
        int krow = gks * 16 + (l >> 5) * 8 + j;
        val = (krow < 576) ? w_conv[oc * 576 + krow] : 0.0f;
    } else {
        val = w_cd[i - WS_WCD];
    }
    ws[i] = f2bf(val);
}

// ---------------- kx: zero-padded bf16 x copy ----------------
__global__ __launch_bounds__(256, 4)
void kx_pad(const float* __restrict__ x, unsigned short* __restrict__ ws) {
    const int ch = blockIdx.x, b = blockIdx.y;
    unsigned short* dst = ws + WS_XPAD + (size_t)(b * 64 + ch) * XPLANE;
    const float* src = x + ((size_t)(b * 64 + ch) << 14);
    for (int i = threadIdx.x; i < XPLANE; i += 256) {
        int r = i / 132, c = i - r * 132;
        float v = 0.0f;
        if (r >= 1 && r <= 128 && c >= 1 && c <= 128)
            v = src[(r - 1) * 128 + (c - 1)];
        dst[i] = f2bf(v);
    }
}

// ---------------- k2: fused 1x1 conv (same as r4) ----------------
__global__ __launch_bounds__(256, 4)
void k2_fused(const float* __restrict__ x, const float* __restrict__ ref,
              const float* __restrict__ b_cd, const unsigned short* __restrict__ wsbf,
              unsigned short* __restrict__ ws) {
    __shared__ __align__(16) char B0[32768];
    const int tid = threadIdx.x, l = tid & 63, w = tid >> 6;
    const int b = blockIdx.y, p0 = blockIdx.x * 128;
    const int rl31 = l & 31, kh8 = (l >> 5) * 8;

    #pragma unroll
    for (int it = 0; it < 8; ++it) {
        int task = it * 256 + tid;
        int kg = task >> 7, px = task & 127;
        const float* src = (kg < 8) ? x : ref;
        int kbase = (kg & 7) * 8;
        unsigned short v[8];
        #pragma unroll
        for (int j = 0; j < 8; ++j)
            v[j] = f2bf(src[(((size_t)b * 64 + kbase + j) << 14) + p0 + px]);
        uint4 pk;
        pk.x = (unsigned)v[0] | ((unsigned)v[1] << 16);
        pk.y = (unsigned)v[2] | ((unsigned)v[3] << 16);
        pk.z = (unsigned)v[4] | ((unsigned)v[5] << 16);
        pk.w = (unsigned)v[6] | ((unsigned)v[7] << 16);
        *(uint4*)(B0 + ((kg >> 1) * 4 + (px >> 5)) * 1024
                      + ((px & 31) + 32 * (kg & 1)) * 16) = pk;
    }
    __syncthreads();

    f32x16 a0, a1;
    #pragma unroll
    for (int r = 0; r < 16; ++r) { a0[r] = 0.0f; a1[r] = 0.0f; }
    const unsigned short* A0 = wsbf + WS_WCD + rl31 * 128 + kh8;
    #pragma unroll
    for (int s = 0; s < 8; ++s) {
        bf16x8 bf = *(bf16x8*)(B0 + ((s * 4 + w) * 64 + l) * 16);
        bf16x8 x0 = *(const bf16x8*)(A0 + s * 16);
        bf16x8 x1 = *(const bf16x8*)(A0 + 32 * 128 + s * 16);
        a0 = MFMA32(x0, bf, a0);
        a1 = MFMA32(x1, bf, a1);
    }
    unsigned short* f2 = ws + WS_F2 + ((size_t)b << 20);
    int px = p0 + w * 32 + rl31;
    #pragma unroll
    for (int t = 0; t < 2; ++t)
        #pragma unroll
        for (int reg = 0; reg < 16; ++reg) {
            int rl = (reg & 3) + 8 * (reg >> 2) + 4 * (l >> 5);
            int ch = t * 32 + rl;
            float v = (t ? a1[reg] : a0[reg]) + b_cd[ch];
            f2[(ch << 14) + px] = f2bf(v);
        }
}

// ---------------- im2col B-stage for k_pm (same as r4) ----------------
__device__ __forceinline__ void stage_B256(char* Bst, const unsigned short* f2b,
                                           int h, int chunk, int tid) {
    int tap = chunk >> 1, cih = (chunk & 1) * 32;
    int dh = tap / 3 - 1, dw = tap % 3 - 1;
    int hs = h + dh;
    #pragma unroll
    for (int it = 0; it < 2; ++it) {
        int task = it * 256 + tid;
        int kg = task >> 7, px = task & 127;
        int wsrc = px + dw;
        unsigned short v[8];
        if (((unsigned)hs < 128u) && ((unsigned)wsrc < 128u)) {
            const unsigned short* r = f2b + ((cih + kg * 8) << 14) + (hs << 7) + wsrc;
            #pragma unroll
            for (int j = 0; j < 8; ++j) v[j] = r[j << 14];
        } else {
            #pragma unroll
            for (int j = 0; j < 8; ++j) v[j] = 0;
        }
        uint4 pk;
        pk.x = (unsigned)v[0] | ((unsigned)v[1] << 16);
        pk.y = (unsigned)v[2] | ((unsigned)v[3] << 16);
        pk.z = (unsigned)v[4] | ((unsigned)v[5] << 16);
        pk.w = (unsigned)v[6] | ((unsigned)v[7] << 16);
        *(uint4*)(Bst + ((kg >> 1) * 4 + (px >> 5)) * 1024
                      + ((px & 31) + 32 * (kg & 1)) * 16) = pk;
    }
}

// ---------------- k_pm: offset/mask GEMM -> u (same as r4) ----------------
__global__ __launch_bounds__(256, 4)
void k_pm(const float* __restrict__ b_p, const float* __restrict__ b_m,
          const unsigned short* __restrict__ wsbf, unsigned short* __restrict__ ws) {
    __shared__ __align__(16) char Bst[8192];
    const int tid = threadIdx.x, l = tid & 63, w = tid >> 6;
    const int h = blockIdx.x, b = blockIdx.y;
    const unsigned short* f2b = wsbf + WS_F2 + ((size_t)b << 20);

    f32x16 acc;
    #pragma unroll
    for (int r = 0; r < 16; ++r) acc[r] = 0.0f;
    #pragma unroll 1
    for (int chunk = 0; chunk < 18; ++chunk) {
        __syncthreads();
        stage_B256(Bst, f2b, h, chunk, tid);
        __syncthreads();
        #pragma unroll
        for (int s = 0; s < 2; ++s) {
            bf16x8 bf = *(bf16x8*)(Bst + ((s * 4 + w) * 64 + l) * 16);
            bf16x8 af = *(const bf16x8*)(wsbf + WS_APM + (((chunk * 2 + s) * 64 + l) << 3));
            acc = MFMA32(af, bf, acc);
        }
    }
    int px = w * 32 + (l & 31);
    unsigned short* up = ws + WS_U + b * 16384 + h * 128 + px;
    #pragma unroll
    for (int reg = 0; reg < 16; ++reg) {
        int rl = (reg & 3) + 8 * (reg >> 2) + 4 * (l >> 5);
        if (rl < 27) {
            float bias = (rl < 18) ? b_p[rl] : b_m[rl - 18];
            up[rl * 65536] = f2bf(acc[reg] + bias);
        }
    }
}

// ---------------- k3: main ----------------
// LDS: FUS [3][128][64] bf16 XOR-swizzled @0 (49152) | TRBC u32[1152] @49152
//      TW fp16x4[1152] @53760 | BCL f32[576] @62976. Total 65280.
//      Reduction overlay @0 (32 KB) after mc loop (FUS dead).
__global__ __launch_bounds__(512, 4)
void k3_main(const float* __restrict__ b_c, const unsigned short* __restrict__ wsbf,
             float* __restrict__ out) {
    __shared__ __align__(16) char lds[65280];
    const int tid = threadIdx.x, l = tid & 63, w = tid >> 6;
    const int mTh = w >> 2, nT = w & 3;
    const int hml = l >> 5, kh8 = hml * 8;
    const int h = blockIdx.x, b = blockIdx.y;
    const unsigned short* f2b = wsbf + WS_F2 + ((size_t)b << 20);
    const int pxN = nT * 32 + (l & 31);

    // ---- fill FUS (swizzled) ----
    #pragma unroll
    for (int it = 0; it < 6; ++it) {
        int t = it * 512 + tid;                 // 3072 tasks: r3(3) x ci(64) x px8(16)
        int r3 = t >> 10, rem = t & 1023;
        int ci = rem >> 4, px8 = rem & 15;
        int hs = h - 1 + r3;
        uint4 v = make_uint4(0u, 0u, 0u, 0u);
        if ((unsigned)hs < 128u)
            v = *(const uint4*)(f2b + (ci << 14) + hs * 128 + px8 * 8);
        const unsigned short* vs = (const unsigned short*)&v;
        #pragma unroll
        for (int e = 0; e < 8; ++e) {
            int px = px8 * 8 + e;
            int cis = ci ^ (e << 3);
            *(unsigned short*)(lds + ((r3 * 128 + px) * 64 + cis) * 2) = vs[e];
        }
    }
    // ---- b_c to LDS ----
    for (int i = tid; i < 576; i += 512) *(float*)(lds + 62976 + i * 4) = b_c[i];
    // ---- tables: idx/dr/dc/m packed u32 + m-premultiplied fp16 weights ----
    for (int i = tid; i < 1152; i += 512) {
        int px = i & 127, n = i >> 7;
        int base = b * 16384 + h * 128 + px;
        float offr = bf2f(wsbf[WS_U + n * 65536 + base]);
        float offc = bf2f(wsbf[WS_U + (9 + n) * 65536 + base]);
        float mraw = bf2f(wsbf[WS_U + (18 + n) * 65536 + base]);
        int nr = n / 3, nc = n - nr * 3;
        float pr = (float)(h + nr) + offr;
        float pc = (float)(px + nc) + offc;
        float flr = floorf(pr), flc = floorf(pc);
        float r0 = fminf(fmaxf(flr, 0.0f), 129.0f);
        float r1 = fminf(fmaxf(flr + 1.0f, 0.0f), 129.0f);
        float c0 = fminf(fmaxf(flc, 0.0f), 129.0f);
        float c1 = fminf(fmaxf(flc + 1.0f, 0.0f), 129.0f);
        float prc = fminf(fmaxf(pr, 0.0f), 129.0f);
        float pcc = fminf(fmaxf(pc, 0.0f), 129.0f);
        float wr0 = 1.0f + r0 - prc, wr1 = 1.0f - (r1 - prc);
        float wc0 = 1.0f + c0 - pcc, wc1 = 1.0f - (c1 - pcc);
        float m = fast_sigmoid(mraw);
        unsigned ir0 = (unsigned)r0, ir1 = (unsigned)r1;
        unsigned ic0 = (unsigned)c0, ic1 = (unsigned)c1;
        unsigned ilt = ir0 * 132u + ic0;
        unsigned dr = ir1 - ir0, dc = ic1 - ic0;      // in {0,1}
        unsigned mb = (unsigned)(__half_as_ushort(__float2half(m)) >> 2);
        *(unsigned*)(lds + 49152 + i * 4) = ilt | (dr << 16) | (dc << 17) | (mb << 18);
        uint2 wpk;
        wpk.x = ((unsigned)__half_as_ushort(__float2half(m * wr0 * wc0)))
              | ((unsigned)__half_as_ushort(__float2half(m * wr1 * wc1)) << 16);
        wpk.y = ((unsigned)__half_as_ushort(__float2half(m * wr0 * wc1)))
              | ((unsigned)__half_as_ushort(__float2half(m * wr1 * wc0)) << 16);
        *(uint2*)(lds + 53760 + i * 8) = wpk;
    }
    __syncthreads();

    // ---- main loop over 5 m-chunks: U-GEMM -> epilogue -> out-GEMM (no syncs) ----
    f32x16 oa[2];
    #pragma unroll
    for (int o = 0; o < 2; ++o)
        #pragma unroll
        for (int r = 0; r < 16; ++r) oa[o][r] = 0.0f;
    const unsigned short* xpb = wsbf + WS_XPAD;

    #pragma unroll 1
    for (int mc = 0; mc < 5; ++mc) {
        f32x16 acc[2];
        #pragma unroll
        for (int mi = 0; mi < 2; ++mi)
            #pragma unroll
            for (int r = 0; r < 16; ++r) acc[mi][r] = 0.0f;

        // U-GEMM: B-frags straight from swizzled FUS, A-frags from global (L2-hot)
        #pragma unroll
        for (int chunk = 0; chunk < 18; ++chunk) {
            const int tap = chunk >> 1;
            const int r3 = tap / 3, dw = tap % 3 - 1;
            const int cibase = (chunk & 1) * 32;
            int pxs = pxN + dw;
            bool valid = (unsigned)pxs < 128u;
            int pxc = min(max(pxs, 0), 127);
            int key = (pxc & 7) << 3;
            #pragma unroll
            for (int s = 0; s < 2; ++s) {
                int cis = (cibase + s * 16 + kh8) ^ key;
                uint4 bv = *(uint4*)(lds + ((r3 * 128 + pxc) * 64 + cis) * 2);
                if (!valid) bv = make_uint4(0u, 0u, 0u, 0u);
                bf16x8 bfrag = u4bf(bv);
                #pragma unroll
                for (int mi = 0; mi < 2; ++mi) {
                    int gmt = mc * 4 + mTh * 2 + mi;
                    bf16x8 af = *(const bf16x8*)
                        (wsbf + WS_AC + (((gmt * 36 + chunk * 2 + s) * 64 + l) << 3));
                    acc[mi] = MFMA32(af, bfrag, acc[mi]);
                }
            }
        }

        // epilogue: +bias, tanh, bilinear sample from xpad, modulate (in regs)
        #pragma unroll
        for (int mi = 0; mi < 2; ++mi) {
            const int rowc = mc * 128 + mTh * 64 + mi * 32;
            #pragma unroll
            for (int rg = 0; rg < 16; ++rg) {
                int rl = (rg & 3) + 8 * (rg >> 2) + 4 * hml;
                int R = rowc + rl;
                int c = R / 9, n = R - 9 * c;
                float uv = acc[mi][rg] + *(const float*)(lds + 62976 + R * 4);
                float t = fast_tanh(uv);
                int e = n * 128 + pxN;
                unsigned rbc = *(const unsigned*)(lds + 49152 + e * 4);
                uint2 wpk = *(const uint2*)(lds + 53760 + e * 8);
                unsigned ilt = rbc & 0xFFFFu;
                unsigned irt = ilt + ((rbc >> 16) & 1u) * 132u;
                unsigned ilb = ilt + ((rbc >> 17) & 1u);
                unsigned irb = irt + ((rbc >> 17) & 1u);
                const unsigned short* xq = xpb + (b * 64 + c) * XPLANE;
                float xlt = bf2f(xq[ilt]), xrb = bf2f(xq[irb]);
                float xlb = bf2f(xq[ilb]), xrt = bf2f(xq[irt]);
                float wlt = __half2float(__ushort_as_half((unsigned short)(wpk.x & 0xFFFF)));
                float wrb = __half2float(__ushort_as_half((unsigned short)(wpk.x >> 16)));
                float wlb = __half2float(__ushort_as_half((unsigned short)(wpk.y & 0xFFFF)));
                float wrt = __half2float(__ushort_as_half((unsigned short)(wpk.y >> 16)));
                float m = __half2float(__ushort_as_half((unsigned short)((rbc >> 18) << 2)));
                float samp = wlt * xlt + wrb * xrb + wlb * xlb + wrt * xrt;
                acc[mi][rg] = samp + m * t;
            }
        }

        // out-GEMM: build B-frags from C-regs via shfl_xor(32), accumulate oa
        #pragma unroll
        for (int mi = 0; mi < 2; ++mi)
            #pragma unroll
            for (int s2 = 0; s2 < 2; ++s2) {
                float kp[4], sd[4], pr[4];
                #pragma unroll
                for (int t = 0; t < 4; ++t) {
                    float lo = acc[mi][s2 * 8 + t], hi = acc[mi][s2 * 8 + 4 + t];
                    kp[t] = hml ? hi : lo;
                    sd[t] = hml ? lo : hi;
                }
                #pragma unroll
                for (int t = 0; t < 4; ++t) pr[t] = __shfl_xor(sd[t], 32);
                float e0 = hml ? pr[0] : kp[0], e1 = hml ? pr[1] : kp[1];
                float e2 = hml ? pr[2] : kp[2], e3 = hml ? pr[3] : kp[3];
                float e4 = hml ? kp[0] : pr[0], e5 = hml ? kp[1] : pr[1];
                float e6 = hml ? kp[2] : pr[2], e7 = hml ? kp[3] : pr[3];
                uint4 bu;
                bu.x = pk16(e0, e1); bu.y = pk16(e2, e3);
                bu.z = pk16(e4, e5); bu.w = pk16(e6, e7);
                bf16x8 bfrag = u4bf(bu);
                int gks = mc * 8 + mTh * 4 + mi * 2 + s2;
                #pragma unroll
                for (int ocT = 0; ocT < 2; ++ocT) {
                    bf16x8 af = *(const bf16x8*)
                        (wsbf + WS_ACONV + (((ocT * 40 + gks) * 64 + l) << 3));
                    oa[ocT] = MFMA32(af, bfrag, oa[ocT]);
                }
            }
    }

    // ---- cross-wave pair reduction (mTh halves) + store ----
    __syncthreads();
    float* red = (float*)lds;
    if (w >= 4) {
        #pragma unroll
        for (int ocT = 0; ocT < 2; ++ocT)
            #pragma unroll
            for (int rg = 0; rg < 16; ++rg)
                red[(((w - 4) * 2 + ocT) * 16 + rg) * 64 + l] = oa[ocT][rg];
    }
    __syncthreads();
    if (w < 4) {
        #pragma unroll
        for (int ocT = 0; ocT < 2; ++ocT)
            #pragma unroll
            for (int rg = 0; rg < 16; ++rg) {
                float v = oa[ocT][rg] + red[((w * 2 + ocT) * 16 + rg) * 64 + l];
                int rl = (rg & 3) + 8 * (rg >> 2) + 4 * hml;
                int oc = ocT * 32 + rl;
                out[(((size_t)b * 64 + oc) << 14) + h * 128 + pxN] = v;
            }
    }
}

extern "C" void kernel_launch(void* const* d_in, const int* in_sizes, int n_in,
                              void* d_out, int out_size, void* d_ws, size_t ws_size,
                              hipStream_t stream) {
    const float* x      = (const float*)d_in[0];
    const float* ref    = (const float*)d_in[1];
    const float* w_cd   = (const float*)d_in[2];
    const float* b_cd   = (const float*)d_in[3];
    const float* w_p    = (const float*)d_in[4];
    const float* b_p    = (const float*)d_in[5];
    const float* w_m    = (const float*)d_in[6];
    const float* b_m    = (const float*)d_in[7];
    const float* w_c    = (const float*)d_in[8];
    const float* b_c    = (const float*)d_in[9];
    const float* w_conv = (const float*)d_in[10];
    float* out = (float*)d_out;
    unsigned short* wsbf = (unsigned short*)d_ws;

    hipLaunchKernelGGL(prep_kernel, dim3(1704), dim3(256), 0, stream,
                       w_c, w_p, w_m, w_conv, w_cd, wsbf);
    hipLaunchKernelGGL(kx_pad, dim3(64, 4), dim3(256), 0, stream, x, wsbf);
    hipLaunchKernelGGL(k2_fused, dim3(128, 4), dim3(256), 0, stream,
                       x, ref, b_cd, wsbf, wsbf);
    hipLaunchKernelGGL(k_pm, dim3(128, 4), dim3(256), 0, stream,
                       b_p, b_m, wsbf, wsbf);
    hipLaunchKernelGGL(k3_main, dim3(128, 4), dim3(512), 0, stream,
                       b_c, wsbf, out);
}